// Round 14
// baseline (51.761 us; speedup 1.0000x reference)
//
#include <hip/hip_runtime.h>

#define MDIM 4096
#define NDIM 4096
#define NCOEF 768
#define ALPHA 16.0f
#define PANEL_U16 (96 * 256 * 8)   // u16 per 256-row panel

typedef __attribute__((ext_vector_type(8))) short bf16x8;
typedef __attribute__((ext_vector_type(4))) float f32x4;

__device__ __forceinline__ unsigned short f2bf(float x) {
    unsigned u = __float_as_uint(x);
    u += 0x7FFFu + ((u >> 16) & 1u);
    return (unsigned short)(u >> 16);
}

__device__ __forceinline__ void glds16(const unsigned short* src, unsigned short* dst) {
    __builtin_amdgcn_global_load_lds(
        (const __attribute__((address_space(1))) void*)src,
        (__attribute__((address_space(3))) void*)dst, 16, 0, 0);
}

// ---- kernel 1 (meta fused): materialize U,V in 256-row PANEL layout ----
__global__ __launch_bounds__(256) void fill_uv(
    const int* __restrict__ fidx, const float* __restrict__ dw,
    unsigned short* __restrict__ U, unsigned short* __restrict__ V)
{
    __shared__ int idx_s[NCOEF];
    __shared__ int dup[8];
    const int b = blockIdx.x;            // (panel*96 + kc)*2 + half
    const int half = b & 1;
    const int pk = b >> 1;               // panel*96 + kc
    const int panel = pk / 96;
    const int kc = pk - panel * 96;
    const int t = threadIdx.x;
    #pragma unroll
    for (int j = 0; j < 3; ++j) idx_s[t + (j << 8)] = fidx[t + (j << 8)];
    if (t < 8) dup[t] = 0;
    __syncthreads();
    {   // dedup (last-write-wins): 32 threads per coef scan 24 q's each
        const int ci = t >> 5;
        const int pci = (kc << 3) + ci;
        const int myidx = idx_s[pci];
        const int q0 = (t & 31) * 24;
        int found = 0;
        #pragma unroll
        for (int s = 0; s < 24; ++s) {
            const int q = q0 + s;
            found |= (q > pci) & (idx_s[q] == myidx);
        }
        if (found) dup[ci] = 1;
    }
    __syncthreads();
    const int rl = (half << 7) + (t >> 1);
    const int row = (panel << 8) + rl;
    const int p0 = (kc << 3) + ((t & 1) << 2);
    const unsigned tt = 2u * (unsigned)row + 1u;
    const float wrev = 1.0f / 16384.0f;
    const float s0 = 0.015625f;
    const float s1 = 0.022097086912079612f;
    unsigned short uo[4], vo[4];
    #pragma unroll
    for (int j = 0; j < 4; ++j) {
        const int p = p0 + j;
        const int idx = idx_s[p];
        const int r = idx >> 12;
        const int c = idx & (NDIM - 1);
        const float su = (r == 0) ? s0 : s1;
        const float sv = (dup[p - (kc << 3)] ? 0.0f : 1.0f) * ALPHA * dw[p]
                         * ((c == 0) ? s0 : s1);
        const unsigned nu = (tt * (unsigned)r) & 16383u;
        const unsigned nv = (tt * (unsigned)c) & 16383u;
        uo[j] = f2bf(su * __builtin_amdgcn_cosf((float)nu * wrev));
        vo[j] = f2bf(sv * __builtin_amdgcn_cosf((float)nv * wrev));
    }
    const size_t o = ((size_t)pk * 256 + rl) * 8 + ((t & 1) << 2);
    *(ushort4*)(U + o) = *(const ushort4*)uo;
    *(ushort4*)(V + o) = *(const ushort4*)vo;
}

// ---- kernel 2: out = W + U @ V^T  (M=N=4096, K=768) ----
// 256x256 tile, 8 waves (2x4), BK=32, 24 iters, 2-buf staging (64 KB) +
// 64 KB W-prefetch LDS region. W rows 0-63 staged via global_load_lds during
// K-iters 0-7 (issued AFTER compute so stage-waits never drain them;
// in-order vmcnt retirement); W rows 64-127 -> regs at iter 21. Epilogue:
// chunks 0-1 W from LDS, 2-3 from wA regs, 4-7 depth-2 wB pipeline with
// loads issued at END of iter c (slot wB[c&1] freed by this iter's read).
__global__ __launch_bounds__(512, 1) void gemm_kernel(
    const float* __restrict__ W,
    const unsigned short* __restrict__ U,
    const unsigned short* __restrict__ V,
    float* __restrict__ out)
{
    __shared__ unsigned short SM[65536];     // 128 KB
    unsigned short* const As = SM;           // 2 bufs x 8192 u16 [0,16384)
    unsigned short* const Bs = SM + 16384;   // 2 bufs x 8192 u16 [16384,32768)
    unsigned short* const Wl = SM + 32768;   // 64 KB W rows 0-63 [32768,65536)

    const int tid = threadIdx.x;         // 0..511
    const int lane = tid & 63;
    const int wave = tid >> 6;           // 0..7

    // XCD rect swizzle: 256 blocks, 8 XCDs, 4(by) x 8(bx) rect per XCD.
    const int bid = blockIdx.x;
    const int xcd = bid & 7;
    const int local = bid >> 3;
    const int by = ((xcd >> 1) << 2) + (local >> 3);   // 0..15
    const int bx = ((xcd & 1) << 3) + (local & 7);     // 0..15
    const int wr = wave >> 2;            // 0..1
    const int wc = wave & 3;             // 0..3
    const int fr = lane & 15;
    const int fks = lane >> 4;

    const unsigned short* uPan = U + (size_t)by * PANEL_U16;
    const unsigned short* vPan = V + (size_t)bx * PANEL_U16;

    f32x4 acc[8][4] = {};

    // LDS fragment offsets (u16): chunk = fks*256 + row
    const int aO = (((fks << 8) + wr * 128 + fr) << 3);
    const int bO = (((fks << 8) + wc * 64 + fr) << 3);

    // epilogue coords
    const int bcol = (bx << 8) + (lane << 2);
    const int erowBase = (by << 8);
    float4 wA[2][4];   // W chunks 2-3, loaded at iter 21
    float4 wB[2][4];   // W chunks 4-7, rotating (load at END of iter c)

#define STAGE(j, buf) do {                                                  \
        const unsigned short* uS = uPan + (size_t)(j) * 8192;               \
        const unsigned short* vS = vPan + (size_t)(j) * 8192;               \
        glds16(uS + ((size_t)tid << 3),        &As[(buf) * 8192 + (wave << 9)]); \
        glds16(uS + 4096 + ((size_t)tid << 3), &As[(buf) * 8192 + 4096 + (wave << 9)]); \
        glds16(vS + ((size_t)tid << 3),        &Bs[(buf) * 8192 + (wave << 9)]); \
        glds16(vS + 4096 + ((size_t)tid << 3), &Bs[(buf) * 8192 + 4096 + (wave << 9)]); \
    } while (0)

#define COMPUTE(buf) do {                                                   \
        bf16x8 a[8], b[4];                                                  \
        _Pragma("unroll")                                                   \
        for (int fm = 0; fm < 8; ++fm)                                      \
            a[fm] = *(const bf16x8*)&As[(buf) * 8192 + aO + (fm << 7)];     \
        _Pragma("unroll")                                                   \
        for (int fn = 0; fn < 4; ++fn)                                      \
            b[fn] = *(const bf16x8*)&Bs[(buf) * 8192 + bO + (fn << 7)];     \
        _Pragma("unroll")                                                   \
        for (int fm = 0; fm < 8; ++fm)                                      \
            _Pragma("unroll")                                               \
            for (int fn = 0; fn < 4; ++fn)                                  \
                acc[fm][fn] = __builtin_amdgcn_mfma_f32_16x16x32_bf16(      \
                    b[fn], a[fm], acc[fm][fn], 0, 0, 0);                    \
    } while (0)

#define VW(n) asm volatile("s_waitcnt vmcnt(" #n ")" ::: "memory")

    STAGE(0, 0);
    #pragma unroll
    for (int j = 0; j < 24; ++j) {
        if (j < 23) STAGE(j + 1, (j + 1) & 1);
        if (j == 21) {
            // W chunks 2-3 (rows 64..127) -> regs; younger than stage 22.
            #pragma unroll
            for (int k = 0; k < 2; ++k)
                #pragma unroll
                for (int i = 0; i < 4; ++i)
                    wA[k][i] = *(const float4*)(
                        W + (size_t)(erowBase + (k + 2) * 32 + wave * 4 + i) * NDIM + bcol);
        }
        // waits: stage j must be done. W-ops are always issued YOUNGER than
        // the awaited stage, so these counts never drain in-flight W loads.
        if (j == 0)       VW(4);
        else if (j <= 8)  VW(5);    // Wl round j-1 (1) + stage j+1 (4)
        else if (j <= 21) VW(4);
        else if (j == 22) VW(12);   // wA (8) + stage 23 (4)
        else              VW(0);
        __builtin_amdgcn_s_barrier();
        asm volatile("" ::: "memory");
        COMPUTE(j & 1);
        if (j < 8) {
            // W-prefetch round j: rows j*8+wave of chunks 0-1 -> Wl (LDS),
            // issued AFTER compute so stage-waits never force-drain them.
            glds16((const unsigned short*)(W + (size_t)(erowBase + j * 8 + wave) * NDIM
                                             + (bx << 8)) + ((size_t)lane << 3),
                   &Wl[j * 4096 + (wave << 9)]);
        }
        if (j < 23) {
            asm volatile("s_waitcnt lgkmcnt(0)" ::: "memory");
            __builtin_amdgcn_s_barrier();
            asm volatile("" ::: "memory");
        }
    }

    // ---- epilogue: out = W + acc, pipelined LDS transpose ----
    // acc[fm][fn][jj] = tile[wr*128+fm*16+fr][wc*64+fn*16+fks*4+jj]
    // chunk c: rows 32c..32c+31, owner wr == c>>2, acc pair (c&3)*2.
    // L: 32 rows x 258 f32 = 33 KB, overlaps As+Bs head (dead). Wl intact.
    // W source: c 0-1 Wl(LDS); c 2-3 wA; c 4-7 wB[c&1], loaded at END of
    // iter c-2 (slot freed by iter c-2's read; no parity collision).
    // vmcnt before reads (in-order retire): ops younger than chunk-c load:
    // c=4,5,6: stores(4)+next load(4)=8; c=7: stores(4)=4.
    float* const L = (float*)SM;
    #pragma unroll
    for (int c = 0; c < 8; ++c) {
        asm volatile("s_waitcnt lgkmcnt(0)" ::: "memory");
        __builtin_amdgcn_s_barrier();    // L free (prev reads / last COMPUTE done)
        asm volatile("" ::: "memory");
        if (wr == (c >> 2)) {
            #pragma unroll
            for (int f2 = 0; f2 < 2; ++f2)
                #pragma unroll
                for (int fn = 0; fn < 4; ++fn)
                    *(f32x4*)(L + (f2 * 16 + fr) * 258 + wc * 64 + fn * 16 + fks * 4)
                        = acc[(c & 3) * 2 + f2][fn];
        }
        asm volatile("s_waitcnt lgkmcnt(0)" ::: "memory");
        __builtin_amdgcn_s_barrier();    // L visible
        asm volatile("" ::: "memory");
        if (c >= 4) {
            if (c < 7) VW(8);            // chunk-c wB load retired
            else       VW(4);
        }
        #pragma unroll
        for (int i = 0; i < 4; ++i) {
            const int rl2 = wave * 4 + i;
            const size_t o = (size_t)(erowBase + c * 32 + rl2) * NDIM + bcol;
            float4 w4;
            if (c < 2) {
                const float* wlds = (const float*)Wl;
                const f32x4 wv = *(const f32x4*)(wlds + (c * 32 + rl2) * 256 + (lane << 2));
                w4.x = wv[0]; w4.y = wv[1]; w4.z = wv[2]; w4.w = wv[3];
            } else if (c < 4) {
                w4 = wA[c - 2][i];
            } else {
                w4 = wB[c & 1][i];
            }
            const f32x4 l4 = *(const f32x4*)(L + rl2 * 258 + (lane << 2));
            float4 r4;
            r4.x = w4.x + l4[0];
            r4.y = w4.y + l4[1];
            r4.z = w4.z + l4[2];
            r4.w = w4.w + l4[3];
            *(float4*)(out + o) = r4;
        }
        if (c >= 2 && c < 6) {
            // W chunk c+2 -> wB[c&1] (slot freed by this iter's read);
            // stays in flight across the next iter's raw barriers.
            #pragma unroll
            for (int i = 0; i < 4; ++i)
                wB[c & 1][i] = *(const float4*)(
                    W + (size_t)(erowBase + (c + 2) * 32 + wave * 4 + i) * NDIM + bcol);
        }
    }
#undef STAGE
#undef COMPUTE
#undef VW
}

extern "C" void kernel_launch(void* const* d_in, const int* in_sizes, int n_in,
                              void* d_out, int out_size, void* d_ws, size_t ws_size,
                              hipStream_t stream) {
    const float* weight = (const float*)d_in[0];
    const float* dw     = (const float*)d_in[1];
    const int*   fidx   = (const int*)d_in[2];
    float* out = (float*)d_out;

    char* ws = (char*)d_ws;
    unsigned short* U = (unsigned short*)ws;                       // 6,291,456 B
    unsigned short* V = (unsigned short*)(ws + 6291456);           // 6,291,456 B

    fill_uv<<<16 * 96 * 2, 256, 0, stream>>>(fidx, dw, U, V);
    gemm_kernel<<<256, 512, 0, stream>>>(weight, U, V, out);
}